// Round 1
// baseline (161.996 us; speedup 1.0000x reference)
//
#include <hip/hip_runtime.h>
#include <hip/hip_bf16.h>

typedef __attribute__((ext_vector_type(4))) float f32x4;
typedef __attribute__((ext_vector_type(8))) short bf16x8;
typedef unsigned short u16;

// ---------- helpers ----------

__device__ __forceinline__ u16 f2bf(float f) {
  union { float f; unsigned int u; } v;
  v.f = f;
  unsigned int r = (v.u + 0x7fffu + ((v.u >> 16) & 1u)) >> 16;
  return (u16)r;
}

// async global->LDS, 16 bytes/lane. LDS dest = wave-uniform base + lane*16.
__device__ __forceinline__ void async16(const void* g, const void* l) {
  __builtin_amdgcn_global_load_lds(
      (const __attribute__((address_space(1))) unsigned int*)(unsigned long)g,
      (__attribute__((address_space(3))) unsigned int*)(unsigned int)(unsigned long)l,
      16, 0, 0);
}

// ---------- 1) plain fp32 -> bf16 convert (Q) ----------

__global__ __launch_bounds__(256) void cvt_plain(const float* __restrict__ in,
                                                 u16* __restrict__ out, int n4) {
  int stride = gridDim.x * blockDim.x;
  for (int i = blockIdx.x * blockDim.x + threadIdx.x; i < n4; i += stride) {
    f32x4 v = *(const f32x4*)(in + (long)i * 4);
    ushort4 o;
    o.x = f2bf(v.x); o.y = f2bf(v.y); o.z = f2bf(v.z); o.w = f2bf(v.w);
    *(ushort4*)(out + (long)i * 4) = o;
  }
}

// ---------- 2) fp32 [R][C] -> bf16 [C][R] transposed convert (K, V) ----------

__global__ __launch_bounds__(256) void cvt_transpose(const float* __restrict__ in,
                                                     u16* __restrict__ out,
                                                     int R, int C) {
  __shared__ u16 tile[64][68];  // pad 68: row stride 136B = 17*8 -> aligned b64 reads
  const long bo = (long)blockIdx.z * (long)R * (long)C;
  const int r0 = blockIdx.y * 64;  // input row base
  const int c0 = blockIdx.x * 64;  // input col base
  const int t = threadIdx.x;
  const int tr = t >> 4;           // 0..15
  const int tc4 = (t & 15) * 4;    // 0,4,...,60

#pragma unroll
  for (int i = 0; i < 4; ++i) {
    int r = i * 16 + tr;
    f32x4 v = *(const f32x4*)(in + bo + (long)(r0 + r) * C + c0 + tc4);
    tile[tc4 + 0][r] = f2bf(v.x);
    tile[tc4 + 1][r] = f2bf(v.y);
    tile[tc4 + 2][r] = f2bf(v.z);
    tile[tc4 + 3][r] = f2bf(v.w);
  }
  __syncthreads();
#pragma unroll
  for (int i = 0; i < 4; ++i) {
    int c = i * 16 + tr;  // output row = input col
    ushort4 u = *(const ushort4*)(&tile[c][tc4]);
    *(ushort4*)(out + bo + (long)(c0 + c) * R + r0 + tc4) = u;
  }
}

// ---------- 3) NT GEMM: C[m][n] = sum_k A[m][k] * Bt[n][k] (bf16 in, f32 acc) ----------

#define BM 128
#define BN 128
#define BK 32

template <bool BF16OUT>
__global__ __launch_bounds__(256, 3) void gemm_nt(const u16* __restrict__ A,
                                                  const u16* __restrict__ Bt,
                                                  void* __restrict__ Cv,
                                                  int M, int N, int K,
                                                  long sA, long sB, long sC) {
  __shared__ u16 As[2][BM][BK];  // 8 KB per buf
  __shared__ u16 Bs[2][BN][BK];  // 8 KB per buf  -> 32 KB total

  const int b = blockIdx.z;
  A  += (long)b * sA;
  Bt += (long)b * sB;

  const int bn0 = blockIdx.x * BN;
  const int bm0 = blockIdx.y * BM;

  const int tid  = threadIdx.x;
  const int lane = tid & 63;
  const int wave = tid >> 6;
  const int wr = wave >> 1;  // 2x2 waves, each owns 64x64
  const int wc = wave & 1;
  const int l16 = lane & 15;
  const int kh  = lane >> 4;  // 0..3

  const u16* Abase = A + (long)bm0 * K;
  const u16* Bbase = Bt + (long)bn0 * K;

  // staging: tile = 128 rows x 32 bf16 = 8192 B = 512 x 16B units
  // unit u: row = u>>2, k-elem = (u&3)*8 ; LDS byte off = u*16 (linear row-major)
  const int u0 = wave * 64 + lane;

  f32x4 acc[4][4] = {};

  const int NT = K / BK;
  int cur = 0;

  // prologue: stage tile 0 into buf 0
#pragma unroll
  for (int i = 0; i < 2; ++i) {
    int u = i * 256 + u0;
    async16(Abase + (long)(u >> 2) * K + (u & 3) * 8,
            (const char*)(&As[0][0][0]) + i * 4096 + wave * 1024);
    async16(Bbase + (long)(u >> 2) * K + (u & 3) * 8,
            (const char*)(&Bs[0][0][0]) + i * 4096 + wave * 1024);
  }
  asm volatile("s_waitcnt vmcnt(0)" ::: "memory");
  __syncthreads();

  for (int t = 0; t < NT; ++t) {
    if (t + 1 < NT) {
      const int k0 = (t + 1) * BK;
      const int nb = cur ^ 1;
#pragma unroll
      for (int i = 0; i < 2; ++i) {
        int u = i * 256 + u0;
        async16(Abase + k0 + (long)(u >> 2) * K + (u & 3) * 8,
                (const char*)(&As[nb][0][0]) + i * 4096 + wave * 1024);
        async16(Bbase + k0 + (long)(u >> 2) * K + (u & 3) * 8,
                (const char*)(&Bs[nb][0][0]) + i * 4096 + wave * 1024);
      }
    }

    // compute current buffer
    bf16x8 af[4], bfr[4];
#pragma unroll
    for (int i = 0; i < 4; ++i) {
      af[i]  = *(const bf16x8*)(&As[cur][wr * 64 + i * 16 + l16][kh * 8]);
      bfr[i] = *(const bf16x8*)(&Bs[cur][wc * 64 + i * 16 + l16][kh * 8]);
    }
#pragma unroll
    for (int i = 0; i < 4; ++i)
#pragma unroll
      for (int j = 0; j < 4; ++j)
        acc[i][j] =
            __builtin_amdgcn_mfma_f32_16x16x32_bf16(af[i], bfr[j], acc[i][j], 0, 0, 0);

    asm volatile("s_waitcnt vmcnt(0)" ::: "memory");
    __syncthreads();
    cur ^= 1;
  }

  // epilogue: C/D layout col = lane&15, row = (lane>>4)*4 + reg
  u16*   Cb = (u16*)Cv + (long)b * sC;
  float* Cf = (float*)Cv + (long)b * sC;
#pragma unroll
  for (int i = 0; i < 4; ++i) {
    const int gm = bm0 + wr * 64 + i * 16 + kh * 4;
#pragma unroll
    for (int j = 0; j < 4; ++j) {
      const int gn = bn0 + wc * 64 + j * 16 + l16;
#pragma unroll
      for (int r = 0; r < 4; ++r) {
        if (BF16OUT)
          Cb[(long)(gm + r) * N + gn] = f2bf(acc[i][j][r]);
        else
          Cf[(long)(gm + r) * N + gn] = acc[i][j][r];
      }
    }
  }
}

// ---------- launch ----------

extern "C" void kernel_launch(void* const* d_in, const int* in_sizes, int n_in,
                              void* d_out, int out_size, void* d_ws, size_t ws_size,
                              hipStream_t stream) {
  const float* Q  = (const float*)d_in[0];
  const float* Kf = (const float*)d_in[1];
  // d_in[2] = span   (unused by the reference's returned value)
  const float* V  = (const float*)d_in[3];
  // d_in[4] = key_pe (unused)
  float* out = (float*)d_out;

  const int B = 8, M = 2048, H = 1024;
  const size_t bmh2 = (size_t)B * M * H * 2;  // bytes of one bf16 [B,M,H]

  // workspace layout (needs 112 MB):
  //   Qb [B][M][H] bf16, Kt [B][H][M] bf16, Vt [B][H][M] bf16, Pt [B][H][H] bf16
  char* ws = (char*)d_ws;
  u16* Qb = (u16*)(ws);
  u16* Kt = (u16*)(ws + bmh2);
  u16* Vt = (u16*)(ws + 2 * bmh2);
  u16* Pt = (u16*)(ws + 3 * bmh2);

  // 1) converts
  cvt_plain<<<2048, 256, 0, stream>>>(Q, Qb, B * M * H / 4);
  cvt_transpose<<<dim3(H / 64, M / 64, B), 256, 0, stream>>>(Kf, Kt, M, H);
  cvt_transpose<<<dim3(H / 64, M / 64, B), 256, 0, stream>>>(V, Vt, M, H);

  // 2) Pt[d][h] = sum_n Vt[d][n] * Kt[h][n]  (= (K^T V)^T), bf16 out
  gemm_nt<true><<<dim3(H / BN, H / BM, B), 256, 0, stream>>>(
      Vt, Kt, (void*)Pt, H, H, M, (long)H * M, (long)H * M, (long)H * H);

  // 3) out[m][d] = sum_h Qb[m][h] * Pt[d][h], f32 out
  gemm_nt<false><<<dim3(H / BN, M / BM, B), 256, 0, stream>>>(
      Qb, Pt, (void*)out, M, H, H, (long)M * H, (long)H * H, (long)M * H);
}

// Round 2
// 151.747 us; speedup vs baseline: 1.0675x; 1.0675x over previous
//
#include <hip/hip_runtime.h>
#include <hip/hip_bf16.h>

typedef __attribute__((ext_vector_type(4))) float f32x4;
typedef __attribute__((ext_vector_type(8))) short bf16x8;
typedef unsigned short u16;

// ---------- helpers ----------

__device__ __forceinline__ u16 f2bf(float f) {
  union { float f; unsigned int u; } v;
  v.f = f;
  unsigned int r = (v.u + 0x7fffu + ((v.u >> 16) & 1u)) >> 16;
  return (u16)r;
}

// async global->LDS, 16 bytes/lane. LDS dest = wave-uniform base + lane*16.
__device__ __forceinline__ void async16(const void* g, const void* l) {
  __builtin_amdgcn_global_load_lds(
      (const __attribute__((address_space(1))) unsigned int*)(unsigned long)g,
      (__attribute__((address_space(3))) unsigned int*)(unsigned int)(unsigned long)l,
      16, 0, 0);
}

// ---------- 1) plain fp32 -> bf16 convert (Q) ----------

__global__ __launch_bounds__(256) void cvt_plain(const float* __restrict__ in,
                                                 u16* __restrict__ out, int n4) {
  int stride = gridDim.x * blockDim.x;
  for (int i = blockIdx.x * blockDim.x + threadIdx.x; i < n4; i += stride) {
    f32x4 v = *(const f32x4*)(in + (long)i * 4);
    ushort4 o;
    o.x = f2bf(v.x); o.y = f2bf(v.y); o.z = f2bf(v.z); o.w = f2bf(v.w);
    *(ushort4*)(out + (long)i * 4) = o;
  }
}

// ---------- 2) fp32 [R][C] -> bf16 [C][R] transposed convert (K, V) ----------

__global__ __launch_bounds__(256) void cvt_transpose(const float* __restrict__ in,
                                                     u16* __restrict__ out,
                                                     int R, int C) {
  __shared__ u16 tile[64][68];  // pad 68: row stride 136B = 17*8 -> aligned b64 reads
  const long bo = (long)blockIdx.z * (long)R * (long)C;
  const int r0 = blockIdx.y * 64;  // input row base
  const int c0 = blockIdx.x * 64;  // input col base
  const int t = threadIdx.x;
  const int tr = t >> 4;           // 0..15
  const int tc4 = (t & 15) * 4;    // 0,4,...,60

#pragma unroll
  for (int i = 0; i < 4; ++i) {
    int r = i * 16 + tr;
    f32x4 v = *(const f32x4*)(in + bo + (long)(r0 + r) * C + c0 + tc4);
    tile[tc4 + 0][r] = f2bf(v.x);
    tile[tc4 + 1][r] = f2bf(v.y);
    tile[tc4 + 2][r] = f2bf(v.z);
    tile[tc4 + 3][r] = f2bf(v.w);
  }
  __syncthreads();
#pragma unroll
  for (int i = 0; i < 4; ++i) {
    int c = i * 16 + tr;  // output row = input col
    ushort4 u = *(const ushort4*)(&tile[c][tc4]);
    *(ushort4*)(out + bo + (long)(c0 + c) * R + r0 + tc4) = u;
  }
}

// ---------- 3) NT GEMM: C[m][n] = sum_k A[m][k] * Bt[n][k] (bf16 in, f32 acc) ----------
// 1D grid, batch = blockIdx.x & 7 (pins each batch to one XCD under round-robin
// dispatch so Pt/Kt panels stay in that XCD's 4MB L2); tile-n fastest within
// batch for A-panel L2 reuse.

#define BM 128
#define BN 128
#define BK 32

template <bool BF16OUT>
__global__ __launch_bounds__(256, 4) void gemm_nt(const u16* __restrict__ A,
                                                  const u16* __restrict__ Bt,
                                                  void* __restrict__ Cv,
                                                  int M, int N, int K,
                                                  long sA, long sB, long sC,
                                                  int nTN) {
  __shared__ u16 As[2][BM][BK];  // 8 KB per buf
  __shared__ u16 Bs[2][BN][BK];  // 8 KB per buf  -> 32 KB total

  const int bid  = blockIdx.x;
  const int b    = bid & 7;        // batch -> XCD
  const int tile = bid >> 3;
  const int bn0 = (tile % nTN) * BN;
  const int bm0 = (tile / nTN) * BM;

  A  += (long)b * sA;
  Bt += (long)b * sB;

  const int tid  = threadIdx.x;
  const int lane = tid & 63;
  const int wave = tid >> 6;
  const int wr = wave >> 1;  // 2x2 waves, each owns 64x64
  const int wc = wave & 1;
  const int l16 = lane & 15;
  const int kh  = lane >> 4;  // 0..3

  const u16* Abase = A + (long)bm0 * K;
  const u16* Bbase = Bt + (long)bn0 * K;

  // staging: tile = 128 rows x 32 bf16 = 8192 B = 512 x 16B units
  // unit u: row = u>>2, k-elem = (u&3)*8 ; LDS byte off = u*16 (linear row-major)
  const int u0 = wave * 64 + lane;

  f32x4 acc[4][4] = {};

  const int NT = K / BK;
  int cur = 0;

  // prologue: stage tile 0 into buf 0
#pragma unroll
  for (int i = 0; i < 2; ++i) {
    int u = i * 256 + u0;
    async16(Abase + (long)(u >> 2) * K + (u & 3) * 8,
            (const char*)(&As[0][0][0]) + i * 4096 + wave * 1024);
    async16(Bbase + (long)(u >> 2) * K + (u & 3) * 8,
            (const char*)(&Bs[0][0][0]) + i * 4096 + wave * 1024);
  }
  asm volatile("s_waitcnt vmcnt(0)" ::: "memory");
  __syncthreads();

  for (int t = 0; t < NT; ++t) {
    if (t + 1 < NT) {
      const int k0 = (t + 1) * BK;
      const int nb = cur ^ 1;
#pragma unroll
      for (int i = 0; i < 2; ++i) {
        int u = i * 256 + u0;
        async16(Abase + k0 + (long)(u >> 2) * K + (u & 3) * 8,
                (const char*)(&As[nb][0][0]) + i * 4096 + wave * 1024);
        async16(Bbase + k0 + (long)(u >> 2) * K + (u & 3) * 8,
                (const char*)(&Bs[nb][0][0]) + i * 4096 + wave * 1024);
      }
    }

    // compute current buffer
    bf16x8 af[4], bfr[4];
#pragma unroll
    for (int i = 0; i < 4; ++i) {
      af[i]  = *(const bf16x8*)(&As[cur][wr * 64 + i * 16 + l16][kh * 8]);
      bfr[i] = *(const bf16x8*)(&Bs[cur][wc * 64 + i * 16 + l16][kh * 8]);
    }
#pragma unroll
    for (int i = 0; i < 4; ++i)
#pragma unroll
      for (int j = 0; j < 4; ++j)
        acc[i][j] =
            __builtin_amdgcn_mfma_f32_16x16x32_bf16(af[i], bfr[j], acc[i][j], 0, 0, 0);

    asm volatile("s_waitcnt vmcnt(0)" ::: "memory");
    __syncthreads();
    cur ^= 1;
  }

  // epilogue: C/D layout col = lane&15, row = (lane>>4)*4 + reg
  u16*   Cb = (u16*)Cv + (long)b * sC;
  float* Cf = (float*)Cv + (long)b * sC;
#pragma unroll
  for (int i = 0; i < 4; ++i) {
    const int gm = bm0 + wr * 64 + i * 16 + kh * 4;
#pragma unroll
    for (int j = 0; j < 4; ++j) {
      const int gn = bn0 + wc * 64 + j * 16 + l16;
#pragma unroll
      for (int r = 0; r < 4; ++r) {
        if (BF16OUT)
          Cb[(long)(gm + r) * N + gn] = f2bf(acc[i][j][r]);
        else
          Cf[(long)(gm + r) * N + gn] = acc[i][j][r];
      }
    }
  }
}

// ---------- launch ----------

extern "C" void kernel_launch(void* const* d_in, const int* in_sizes, int n_in,
                              void* d_out, int out_size, void* d_ws, size_t ws_size,
                              hipStream_t stream) {
  const float* Q  = (const float*)d_in[0];
  const float* Kf = (const float*)d_in[1];
  // d_in[2] = span   (unused by the reference's returned value)
  const float* V  = (const float*)d_in[3];
  // d_in[4] = key_pe (unused)
  float* out = (float*)d_out;

  const int B = 8, M = 2048, H = 1024;
  const size_t bmh2 = (size_t)B * M * H * 2;  // bytes of one bf16 [B,M,H]

  // workspace layout (needs 112 MB):
  //   Qb [B][M][H] bf16, Kt [B][H][M] bf16, Vt [B][H][M] bf16, Pt [B][H][H] bf16
  char* ws = (char*)d_ws;
  u16* Qb = (u16*)(ws);
  u16* Kt = (u16*)(ws + bmh2);
  u16* Vt = (u16*)(ws + 2 * bmh2);
  u16* Pt = (u16*)(ws + 3 * bmh2);

  // 1) converts
  cvt_plain<<<2048, 256, 0, stream>>>(Q, Qb, B * M * H / 4);
  cvt_transpose<<<dim3(H / 64, M / 64, B), 256, 0, stream>>>(Kf, Kt, M, H);
  cvt_transpose<<<dim3(H / 64, M / 64, B), 256, 0, stream>>>(V, Vt, M, H);

  // 2) Pt[d][h] = sum_n Vt[d][n] * Kt[h][n]  (= (K^T V)^T), bf16 out
  //    grid = B * (H/BM) * (H/BN), batch = bid & 7
  gemm_nt<true><<<B * (H / BM) * (H / BN), 256, 0, stream>>>(
      Vt, Kt, (void*)Pt, H, H, M, (long)H * M, (long)H * M, (long)H * H, H / BN);

  // 3) out[m][d] = sum_h Qb[m][h] * Pt[d][h], f32 out
  gemm_nt<false><<<B * (M / BM) * (H / BN), 256, 0, stream>>>(
      Qb, Pt, (void*)out, M, H, H, (long)M * H, (long)H * H, (long)M * H, H / BN);
}

// Round 3
// 143.312 us; speedup vs baseline: 1.1304x; 1.0589x over previous
//
#include <hip/hip_runtime.h>
#include <hip/hip_bf16.h>

typedef __attribute__((ext_vector_type(4))) float f32x4;
typedef __attribute__((ext_vector_type(8))) short bf16x8;
typedef unsigned short u16;

// ---------- helpers ----------

__device__ __forceinline__ u16 f2bf(float f) {
  union { float f; unsigned int u; } v;
  v.f = f;
  unsigned int r = (v.u + 0x7fffu + ((v.u >> 16) & 1u)) >> 16;
  return (u16)r;
}

// async global->LDS, 16 bytes/lane. LDS dest = wave-uniform base + lane*16.
__device__ __forceinline__ void async16(const void* g, const void* l) {
  __builtin_amdgcn_global_load_lds(
      (const __attribute__((address_space(1))) unsigned int*)(unsigned long)g,
      (__attribute__((address_space(3))) unsigned int*)(unsigned int)(unsigned long)l,
      16, 0, 0);
}

// ---------- 1) plain fp32 -> bf16 convert (Q) ----------

__global__ __launch_bounds__(256) void cvt_plain(const float* __restrict__ in,
                                                 u16* __restrict__ out, int n4) {
  int stride = gridDim.x * blockDim.x;
  for (int i = blockIdx.x * blockDim.x + threadIdx.x; i < n4; i += stride) {
    f32x4 v = *(const f32x4*)(in + (long)i * 4);
    ushort4 o;
    o.x = f2bf(v.x); o.y = f2bf(v.y); o.z = f2bf(v.z); o.w = f2bf(v.w);
    *(ushort4*)(out + (long)i * 4) = o;
  }
}

// ---------- 2) fp32 [R][C] -> bf16 [C][R] transposed convert (K, V) ----------

__global__ __launch_bounds__(256) void cvt_transpose(const float* __restrict__ in,
                                                     u16* __restrict__ out,
                                                     int R, int C) {
  __shared__ u16 tile[64][68];
  const long bo = (long)blockIdx.z * (long)R * (long)C;
  const int r0 = blockIdx.y * 64;
  const int c0 = blockIdx.x * 64;
  const int t = threadIdx.x;
  const int tr = t >> 4;
  const int tc4 = (t & 15) * 4;

#pragma unroll
  for (int i = 0; i < 4; ++i) {
    int r = i * 16 + tr;
    f32x4 v = *(const f32x4*)(in + bo + (long)(r0 + r) * C + c0 + tc4);
    tile[tc4 + 0][r] = f2bf(v.x);
    tile[tc4 + 1][r] = f2bf(v.y);
    tile[tc4 + 2][r] = f2bf(v.z);
    tile[tc4 + 3][r] = f2bf(v.w);
  }
  __syncthreads();
#pragma unroll
  for (int i = 0; i < 4; ++i) {
    int c = i * 16 + tr;
    ushort4 u = *(const ushort4*)(&tile[c][tc4]);
    *(ushort4*)(out + bo + (long)(c0 + c) * R + r0 + tc4) = u;
  }
}

// ---------- 3) NT GEMM, 3-buffer 4-phase counted-vmcnt schedule ----------
// C[m][n] = sum_k A[m][k] * Bt[n][k]; BM=256, BN=128, BK=64, 512 thr (8 waves 4Mx2N),
// per-wave 64x64 (4x4 frags of 16x16x32). LDS 3 buffers: depth-2 prefetch so the
// boundary wait is vmcnt(6) on loads issued a full tile earlier (never a fresh drain).
// Read swizzle: 16B-slot s' = s ^ (row&7); global_load_lds writes linearly, so the
// per-lane GLOBAL source is inverse-permuted (rule 21).

#define ASTRIDE (256 * 64)      /* elements per A buffer */
#define BSTRIDE (128 * 64)

#define LD_A(c, f, ks) (*(const bf16x8*)((const u16*)As + (c)*ASTRIDE + offA[f][ks]))
#define LD_B(c, f, ks) (*(const bf16x8*)((const u16*)Bs + (c)*BSTRIDE + offB[f][ks]))
#define STG_A(i, buf) async16(srcA[i], (const char*)As + (buf)*(ASTRIDE * 2) + dstA[i])
#define STG_B(i, buf) async16(srcB[i], (const char*)Bs + (buf)*(BSTRIDE * 2) + dstB[i])
#define MF(am, bn, fm, fn) \
  acc[fm][fn] = __builtin_amdgcn_mfma_f32_16x16x32_bf16(am, bn, acc[fm][fn], 0, 0, 0)

template <bool BF16OUT>
__global__ __launch_bounds__(512, 2) void gemm8(const u16* __restrict__ A,
                                                const u16* __restrict__ Bt,
                                                void* __restrict__ Cv,
                                                int M, int N, int K,
                                                long sA, long sB, long sC,
                                                int nTN) {
  __shared__ u16 As[3][256][64];  // 96 KB
  __shared__ u16 Bs[3][128][64];  // 48 KB

  const int bid  = blockIdx.x;
  const int b    = bid & 7;       // batch -> XCD pin
  const int tile = bid >> 3;
  const int bn0 = (tile % nTN) * 128;
  const int bm0 = (tile / nTN) * 256;

  const u16* Ab = A + (long)b * sA + (long)bm0 * K;
  const u16* Bb = Bt + (long)b * sB + (long)bn0 * K;

  const int tid  = threadIdx.x;
  const int lane = tid & 63;
  const int wave = tid >> 6;   // 0..7
  const int wr   = wave >> 1;  // 0..3 (M)
  const int wc   = wave & 1;   // 0..1 (N)
  const int l16  = lane & 15;
  const int kh   = lane >> 4;  // 0..3

  // stage sources (global, swizzle-inverse) + LDS dests (linear)
  const char* srcA[4];
  const char* srcB[2];
  int dstA[4], dstB[2];
#pragma unroll
  for (int i = 0; i < 4; ++i) {
    int u = tid + i * 512;                      // 0..2047
    int row = u >> 3, sl = (u & 7) ^ (row & 7);
    srcA[i] = (const char*)(Ab + (long)row * K) + sl * 16;
    dstA[i] = u * 16;
  }
#pragma unroll
  for (int i = 0; i < 2; ++i) {
    int u = tid + i * 512;                      // 0..1023
    int row = u >> 3, sl = (u & 7) ^ (row & 7);
    srcB[i] = (const char*)(Bb + (long)row * K) + sl * 16;
    dstB[i] = u * 16;
  }

  // fragment LDS element offsets (swizzled read side)
  int offA[4][2], offB[4][2];
#pragma unroll
  for (int f = 0; f < 4; ++f) {
    int rA = wr * 64 + f * 16 + l16;
    int rB = wc * 64 + f * 16 + l16;
#pragma unroll
    for (int ks = 0; ks < 2; ++ks) {
      offA[f][ks] = rA * 64 + (((ks * 4 + kh) ^ (rA & 7)) * 8);
      offB[f][ks] = rB * 64 + (((ks * 4 + kh) ^ (rB & 7)) * 8);
    }
  }

  f32x4 acc[4][4] = {};
  const int NT = K / 64;

  // prologue: stage tiles 0 and 1
#pragma unroll
  for (int i = 0; i < 4; ++i) STG_A(i, 0);
#pragma unroll
  for (int i = 0; i < 2; ++i) STG_B(i, 0);
#pragma unroll
  for (int i = 0; i < 4; ++i) srcA[i] += 128;
#pragma unroll
  for (int i = 0; i < 2; ++i) srcB[i] += 128;
#pragma unroll
  for (int i = 0; i < 4; ++i) STG_A(i, 1);
#pragma unroll
  for (int i = 0; i < 2; ++i) STG_B(i, 1);
#pragma unroll
  for (int i = 0; i < 4; ++i) srcA[i] += 128;
#pragma unroll
  for (int i = 0; i < 2; ++i) srcB[i] += 128;
  asm volatile("s_waitcnt vmcnt(6)" ::: "memory");  // tile 0 resident
  __builtin_amdgcn_s_barrier();

  int c = 0, nb = 2;
  for (int t = 0; t < NT; ++t) {
    const bool st = (t + 2) < NT;

    // ---- phase 0: ks=0, fm 0-1 ----
    bf16x8 a0 = LD_A(c, 0, 0), a1 = LD_A(c, 1, 0);
    bf16x8 b0 = LD_B(c, 0, 0), b1 = LD_B(c, 1, 0);
    bf16x8 b2 = LD_B(c, 2, 0), b3 = LD_B(c, 3, 0);
    if (st) { STG_A(0, nb); STG_A(1, nb); }
    asm volatile("" ::: "memory");
    __builtin_amdgcn_s_barrier();
    __builtin_amdgcn_s_setprio(1);
    MF(a0, b0, 0, 0); MF(a0, b1, 0, 1); MF(a0, b2, 0, 2); MF(a0, b3, 0, 3);
    MF(a1, b0, 1, 0); MF(a1, b1, 1, 1); MF(a1, b2, 1, 2); MF(a1, b3, 1, 3);
    __builtin_amdgcn_s_setprio(0);

    // ---- phase 1: ks=0, fm 2-3 ----
    bf16x8 a2 = LD_A(c, 2, 0), a3 = LD_A(c, 3, 0);
    if (st) { STG_A(2, nb); STG_A(3, nb); }
    asm volatile("" ::: "memory");
    __builtin_amdgcn_s_barrier();
    __builtin_amdgcn_s_setprio(1);
    MF(a2, b0, 2, 0); MF(a2, b1, 2, 1); MF(a2, b2, 2, 2); MF(a2, b3, 2, 3);
    MF(a3, b0, 3, 0); MF(a3, b1, 3, 1); MF(a3, b2, 3, 2); MF(a3, b3, 3, 3);
    __builtin_amdgcn_s_setprio(0);

    // ---- phase 2: ks=1, fm 0-1 ----
    a0 = LD_A(c, 0, 1); a1 = LD_A(c, 1, 1);
    b0 = LD_B(c, 0, 1); b1 = LD_B(c, 1, 1);
    b2 = LD_B(c, 2, 1); b3 = LD_B(c, 3, 1);
    if (st) STG_B(0, nb);
    asm volatile("" ::: "memory");
    __builtin_amdgcn_s_barrier();
    __builtin_amdgcn_s_setprio(1);
    MF(a0, b0, 0, 0); MF(a0, b1, 0, 1); MF(a0, b2, 0, 2); MF(a0, b3, 0, 3);
    MF(a1, b0, 1, 0); MF(a1, b1, 1, 1); MF(a1, b2, 1, 2); MF(a1, b3, 1, 3);
    __builtin_amdgcn_s_setprio(0);

    // ---- phase 3: ks=1, fm 2-3 (tile boundary) ----
    a2 = LD_A(c, 2, 1); a3 = LD_A(c, 3, 1);
    if (st) STG_B(1, nb);
#pragma unroll
    for (int i = 0; i < 4; ++i) srcA[i] += 128;
#pragma unroll
    for (int i = 0; i < 2; ++i) srcB[i] += 128;
    if (st) asm volatile("s_waitcnt vmcnt(6)" ::: "memory");   // keep t+2 in flight, t+1 resident
    else    asm volatile("s_waitcnt vmcnt(0)" ::: "memory");   // pipeline drain (loads are old)
    asm volatile("s_waitcnt lgkmcnt(0)" ::: "memory");         // cross-wave WAR guard
    __builtin_amdgcn_s_barrier();
    __builtin_amdgcn_s_setprio(1);
    MF(a2, b0, 2, 0); MF(a2, b1, 2, 1); MF(a2, b2, 2, 2); MF(a2, b3, 2, 3);
    MF(a3, b0, 3, 0); MF(a3, b1, 3, 1); MF(a3, b2, 3, 2); MF(a3, b3, 3, 3);
    __builtin_amdgcn_s_setprio(0);

    c = (c == 2) ? 0 : c + 1;
    nb = (nb == 2) ? 0 : nb + 1;
  }

  // epilogue: C/D layout col = lane&15, row = (lane>>4)*4 + reg
  u16*   Cb = (u16*)Cv + (long)b * sC;
  float* Cf = (float*)Cv + (long)b * sC;
#pragma unroll
  for (int fm = 0; fm < 4; ++fm) {
    const int gm = bm0 + wr * 64 + fm * 16 + kh * 4;
#pragma unroll
    for (int fn = 0; fn < 4; ++fn) {
      const int gn = bn0 + wc * 64 + fn * 16 + l16;
#pragma unroll
      for (int r = 0; r < 4; ++r) {
        if (BF16OUT) Cb[(long)(gm + r) * N + gn] = f2bf(acc[fm][fn][r]);
        else         Cf[(long)(gm + r) * N + gn] = acc[fm][fn][r];
      }
    }
  }
}

// ---------- launch ----------

extern "C" void kernel_launch(void* const* d_in, const int* in_sizes, int n_in,
                              void* d_out, int out_size, void* d_ws, size_t ws_size,
                              hipStream_t stream) {
  const float* Q  = (const float*)d_in[0];
  const float* Kf = (const float*)d_in[1];
  // d_in[2] = span   (unused by the reference's returned value)
  const float* V  = (const float*)d_in[3];
  // d_in[4] = key_pe (unused)
  float* out = (float*)d_out;

  const int B = 8, M = 2048, H = 1024;
  const size_t bmh2 = (size_t)B * M * H * 2;

  // workspace: Qb [B][M][H] bf16, Kt [B][H][M] bf16, Vt [B][H][M] bf16, Pt [B][H][H] bf16
  char* ws = (char*)d_ws;
  u16* Qb = (u16*)(ws);
  u16* Kt = (u16*)(ws + bmh2);
  u16* Vt = (u16*)(ws + 2 * bmh2);
  u16* Pt = (u16*)(ws + 3 * bmh2);

  cvt_plain<<<2048, 256, 0, stream>>>(Q, Qb, B * M * H / 4);
  cvt_transpose<<<dim3(H / 64, M / 64, B), 256, 0, stream>>>(Kf, Kt, M, H);
  cvt_transpose<<<dim3(H / 64, M / 64, B), 256, 0, stream>>>(V, Vt, M, H);

  // Pt[d][h] = sum_n Vt[d][n] * Kt[h][n]   (M=1024, N=1024, K=2048) -> 256 blocks
  gemm8<true><<<8 * (1024 / 256) * (1024 / 128), 512, 0, stream>>>(
      Vt, Kt, (void*)Pt, 1024, 1024, 2048, (long)H * M, (long)H * M, (long)H * H,
      1024 / 128);

  // out[m][d] = sum_h Qb[m][h] * Pt[d][h]  (M=2048, N=1024, K=1024) -> 512 blocks
  gemm8<false><<<8 * (2048 / 256) * (1024 / 128), 512, 0, stream>>>(
      Qb, Pt, (void*)out, 2048, 1024, 1024, (long)M * H, (long)H * H, (long)M * H,
      1024 / 128);
}

// Round 4
// 141.034 us; speedup vs baseline: 1.1486x; 1.0161x over previous
//
#include <hip/hip_runtime.h>
#include <hip/hip_bf16.h>

typedef __attribute__((ext_vector_type(4))) float f32x4;
typedef __attribute__((ext_vector_type(8))) short bf16x8;
typedef unsigned short u16;

// ---------- helpers ----------

__device__ __forceinline__ u16 f2bf(float f) {
  union { float f; unsigned int u; } v;
  v.f = f;
  unsigned int r = (v.u + 0x7fffu + ((v.u >> 16) & 1u)) >> 16;
  return (u16)r;
}

// async global->LDS, 16 bytes/lane. LDS dest = wave-uniform base + lane*16.
__device__ __forceinline__ void async16(const void* g, const void* l) {
  __builtin_amdgcn_global_load_lds(
      (const __attribute__((address_space(1))) unsigned int*)(unsigned long)g,
      (__attribute__((address_space(3))) unsigned int*)(unsigned int)(unsigned long)l,
      16, 0, 0);
}

// ---------- 1) plain fp32 -> bf16 convert (Q) ----------

__global__ __launch_bounds__(256) void cvt_plain(const float* __restrict__ in,
                                                 u16* __restrict__ out, int n4) {
  int stride = gridDim.x * blockDim.x;
  for (int i = blockIdx.x * blockDim.x + threadIdx.x; i < n4; i += stride) {
    f32x4 v = *(const f32x4*)(in + (long)i * 4);
    ushort4 o;
    o.x = f2bf(v.x); o.y = f2bf(v.y); o.z = f2bf(v.z); o.w = f2bf(v.w);
    *(ushort4*)(out + (long)i * 4) = o;
  }
}

// ---------- 2) fp32 [R][C] -> bf16 [C][R] transposed convert (K, V) ----------

__global__ __launch_bounds__(256) void cvt_transpose(const float* __restrict__ in,
                                                     u16* __restrict__ out,
                                                     int R, int C) {
  __shared__ u16 tile[64][68];
  const long bo = (long)blockIdx.z * (long)R * (long)C;
  const int r0 = blockIdx.y * 64;
  const int c0 = blockIdx.x * 64;
  const int t = threadIdx.x;
  const int tr = t >> 4;
  const int tc4 = (t & 15) * 4;

#pragma unroll
  for (int i = 0; i < 4; ++i) {
    int r = i * 16 + tr;
    f32x4 v = *(const f32x4*)(in + bo + (long)(r0 + r) * C + c0 + tc4);
    tile[tc4 + 0][r] = f2bf(v.x);
    tile[tc4 + 1][r] = f2bf(v.y);
    tile[tc4 + 2][r] = f2bf(v.z);
    tile[tc4 + 3][r] = f2bf(v.w);
  }
  __syncthreads();
#pragma unroll
  for (int i = 0; i < 4; ++i) {
    int c = i * 16 + tr;
    ushort4 u = *(const ushort4*)(&tile[c][tc4]);
    *(ushort4*)(out + bo + (long)(c0 + c) * R + r0 + tc4) = u;
  }
}

// ---------- 3) NT GEMM, 8-phase (m201-style) schedule ----------
// C[m][n] = sum_k A[m][k]*Bt[n][k]. 512 thr = 8 waves (2M x 4N).
// Half-aligned fragments: per-wave frag fm<FM/2 lives in A-half0, else A-half1
// (same for fn/B). Each quadrant phase (qm,qn) reads exactly one A-half and one
// B-half -> per-tile stage/release schedule with ONE counted vmcnt per K-tile.
// LDS read swizzle: 16B-slot s' = s ^ (row&7); staging pre-swizzles the global
// source (both-sides rule), LDS writes stay linear for global_load_lds.

#define BARRIER()                                   \
  {                                                 \
    asm volatile("" ::: "memory");                  \
    __builtin_amdgcn_s_barrier();                   \
    asm volatile("" ::: "memory");                  \
  }

#define STG_A(h, buf)                                                         \
  {                                                                           \
    _Pragma("unroll") for (int i_ = 0; i_ < LA; ++i_) {                       \
      async16(Ab + aoff[h][i_],                                               \
              (char*)&As[buf][h][0][0] + (tid + i_ * 512) * 16);              \
      aoff[h][i_] += 128;                                                     \
    }                                                                         \
  }

#define STG_B(h, buf)                                                         \
  {                                                                           \
    _Pragma("unroll") for (int i_ = 0; i_ < LB; ++i_) {                       \
      async16(Bb + boff[h][i_],                                               \
              (char*)&Bs[buf][h][0][0] + (tid + i_ * 512) * 16);              \
      boff[h][i_] += 128;                                                     \
    }                                                                         \
  }

#define LDA_Q(buf, qm)                                                        \
  {                                                                           \
    _Pragma("unroll") for (int f_ = 0; f_ < HM; ++f_) {                       \
      areg[f_][0] = *(const bf16x8*)&As[buf][qm][wrA + f_ * 16][sw0];         \
      areg[f_][1] = *(const bf16x8*)&As[buf][qm][wrA + f_ * 16][sw1];         \
    }                                                                         \
  }

#define LDB_Q(buf, qn)                                                        \
  {                                                                           \
    _Pragma("unroll") for (int g_ = 0; g_ < HN; ++g_) {                       \
      breg[qn * HN + g_][0] = *(const bf16x8*)&Bs[buf][qn][wcB + g_ * 16][sw0]; \
      breg[qn * HN + g_][1] = *(const bf16x8*)&Bs[buf][qn][wcB + g_ * 16][sw1]; \
    }                                                                         \
  }

#define MMA_Q(qm, qn)                                                         \
  {                                                                           \
    __builtin_amdgcn_s_setprio(1);                                            \
    _Pragma("unroll") for (int f_ = 0; f_ < HM; ++f_)                         \
    _Pragma("unroll") for (int g_ = 0; g_ < HN; ++g_)                         \
    _Pragma("unroll") for (int k_ = 0; k_ < 2; ++k_)                          \
      acc[qm * HM + f_][qn * HN + g_] =                                       \
          __builtin_amdgcn_mfma_f32_16x16x32_bf16(                            \
              areg[f_][k_], breg[qn * HN + g_][k_],                           \
              acc[qm * HM + f_][qn * HN + g_], 0, 0, 0);                      \
    __builtin_amdgcn_s_setprio(0);                                            \
  }

#define VMC_LA()                                                              \
  {                                                                           \
    if constexpr (LA == 2) asm volatile("s_waitcnt vmcnt(2)" ::: "memory");   \
    else asm volatile("s_waitcnt vmcnt(1)" ::: "memory");                     \
  }

#define VMC_STEADY()                                                          \
  {                                                                           \
    if (more) VMC_LA()                                                        \
    else asm volatile("s_waitcnt vmcnt(0)" ::: "memory");                     \
  }

// TILE: compute K-tile from buf `cur`; stage (t+1).{Ah1,Bh0,Bh1} -> `nxt` if g01,
// (t+2).Ah0 -> `cur` if g23; boundary wait `vm` before last pre-MFMA barrier.
#define TILE(cur, nxt, g01, g23, vm)                                          \
  {                                                                           \
    /* phase (0,0): A-half0 x B-half0 */                                      \
    LDA_Q(cur, 0); LDB_Q(cur, 0);                                             \
    if (g01) STG_A(1, nxt);                                                   \
    BARRIER(); MMA_Q(0, 0); BARRIER();                                        \
    /* phase (0,1): A-half0 x B-half1 */                                      \
    LDB_Q(cur, 1);                                                            \
    if (g01) STG_B(0, nxt);                                                   \
    BARRIER(); MMA_Q(0, 1); BARRIER();                                        \
    /* phase (1,0): A-half1 x B-half0 */                                      \
    LDA_Q(cur, 1);                                                            \
    if (g01) STG_B(1, nxt);                                                   \
    BARRIER(); MMA_Q(1, 0); BARRIER();                                        \
    /* phase (1,1): A-half1 x B-half1 (tile boundary) */                      \
    if (g23) STG_A(0, cur);                                                   \
    vm;                                                                       \
    BARRIER(); MMA_Q(1, 1); BARRIER();                                        \
  }

template <int BM, int BN, bool BF16OUT>
__global__ __launch_bounds__(512, 2) void gemm8p(const u16* __restrict__ A,
                                                 const u16* __restrict__ Bt,
                                                 void* __restrict__ Cv,
                                                 int N, int K,
                                                 long sA, long sB, long sC,
                                                 int nTN) {
  constexpr int FM = BM / 32;      // per-wave M frags (WM=2)
  constexpr int FN = BN / 64;      // per-wave N frags (WN=4)
  constexpr int HM = FM / 2, HN = FN / 2;
  constexpr int LA = BM / 128, LB = BN / 128;   // gload16 per thread per half

  __shared__ u16 As[2][2][BM / 2][64];
  __shared__ u16 Bs[2][2][BN / 2][64];

  const int bid = blockIdx.x;
  const int b = bid & 7;            // batch -> XCD pin
  const int tile = bid >> 3;
  const int bn0 = (tile % nTN) * BN;
  const int bm0 = (tile / nTN) * BM;

  const char* Ab = (const char*)(A + (long)b * sA);
  const char* Bb = (const char*)(Bt + (long)b * sB);

  const int tid = threadIdx.x;
  const int lane = tid & 63;
  const int wave = tid >> 6;   // 0..7
  const int wr = wave >> 2;    // 0..1
  const int wc = wave & 3;     // 0..3
  const int l16 = lane & 15;
  const int kh = lane >> 4;

  const int wrA = wr * (HM * 16) + l16;   // row-in-half base (A)
  const int wcB = wc * (HN * 16) + l16;   // row-in-half base (B)
  const int sw0 = (kh ^ (l16 & 7)) * 8;   // swizzled k-slot, ks=0 (elems)
  const int sw1 = ((4 + kh) ^ (l16 & 7)) * 8;

  // staging byte-offsets into batch slab, per half per load
  int aoff[2][LA], boff[2][LB];
#pragma unroll
  for (int h = 0; h < 2; ++h)
#pragma unroll
    for (int i = 0; i < LA; ++i) {
      int u = tid + i * 512;
      int row = u >> 3, sl = (u & 7) ^ (row & 7);
      aoff[h][i] = (bm0 + h * (BM / 2) + row) * (K * 2) + sl * 16;
    }
#pragma unroll
  for (int h = 0; h < 2; ++h)
#pragma unroll
    for (int i = 0; i < LB; ++i) {
      int u = tid + i * 512;
      int row = u >> 3, sl = (u & 7) ^ (row & 7);
      boff[h][i] = (bn0 + h * (BN / 2) + row) * (K * 2) + sl * 16;
    }

  f32x4 acc[FM][FN] = {};
  bf16x8 areg[HM][2], breg[FN][2];

  const int NT = K / 64;

  // prologue: tile0 all halves -> buf0, tile1 Ah0 -> buf1
  STG_A(0, 0); STG_A(1, 0); STG_B(0, 0); STG_B(1, 0);
  STG_A(0, 1);
  VMC_LA();
  BARRIER();

  for (int it = 0; it < NT / 2; ++it) {
    const bool more = (it + 1 < NT / 2);
    TILE(0, 1, true, more, VMC_STEADY());
    TILE(1, 0, more, more, VMC_STEADY());
  }

  // epilogue: C/D layout col = lane&15, row = kh*4 + r
  u16*   Cb = (u16*)Cv + (long)b * sC;
  float* Cf = (float*)Cv + (long)b * sC;
#pragma unroll
  for (int fm = 0; fm < FM; ++fm) {
    const int gm = bm0 + (fm / HM) * (BM / 2) + wr * (HM * 16) + (fm % HM) * 16 + kh * 4;
#pragma unroll
    for (int fn = 0; fn < FN; ++fn) {
      const int gn = bn0 + (fn / HN) * (BN / 2) + wc * (HN * 16) + (fn % HN) * 16 + l16;
#pragma unroll
      for (int r = 0; r < 4; ++r) {
        if (BF16OUT) Cb[(long)(gm + r) * N + gn] = f2bf(acc[fm][fn][r]);
        else         Cf[(long)(gm + r) * N + gn] = acc[fm][fn][r];
      }
    }
  }
}

// ---------- launch ----------

extern "C" void kernel_launch(void* const* d_in, const int* in_sizes, int n_in,
                              void* d_out, int out_size, void* d_ws, size_t ws_size,
                              hipStream_t stream) {
  const float* Q  = (const float*)d_in[0];
  const float* Kf = (const float*)d_in[1];
  // d_in[2] = span   (unused by the reference's returned value)
  const float* V  = (const float*)d_in[3];
  // d_in[4] = key_pe (unused)
  float* out = (float*)d_out;

  const int B = 8, M = 2048, H = 1024;
  const size_t bmh2 = (size_t)B * M * H * 2;

  // workspace: Qb [B][M][H] bf16, Kt [B][H][M] bf16, Vt [B][H][M] bf16, Pt [B][H][H] bf16
  char* ws = (char*)d_ws;
  u16* Qb = (u16*)(ws);
  u16* Kt = (u16*)(ws + bmh2);
  u16* Vt = (u16*)(ws + 2 * bmh2);
  u16* Pt = (u16*)(ws + 3 * bmh2);

  cvt_plain<<<2048, 256, 0, stream>>>(Q, Qb, B * M * H / 4);
  cvt_transpose<<<dim3(H / 64, M / 64, B), 256, 0, stream>>>(Kf, Kt, M, H);
  cvt_transpose<<<dim3(H / 64, M / 64, B), 256, 0, stream>>>(V, Vt, M, H);

  // GEMM A: Pt[d][h] = sum_n Vt[d][n]*Kt[h][n]  (M=1024,N=1024,K=2048)
  // BM=128,BN=256 -> 8*4 tiles * 8 batches = 256 blocks (full GPU)
  gemm8p<128, 256, true><<<256, 512, 0, stream>>>(
      Vt, Kt, (void*)Pt, 1024, 2048, (long)H * M, (long)H * M, (long)H * H, 4);

  // GEMM B: out[m][d] = sum_h Qb[m][h]*Pt[d][h] (M=2048,N=1024,K=1024)
  // BM=256,BN=256 -> 8*4 tiles * 8 batches = 256 blocks (full GPU)
  gemm8p<256, 256, false><<<256, 512, 0, stream>>>(
      Qb, Pt, (void*)out, 1024, 1024, (long)M * H, (long)H * H, (long)M * H, 4);
}

// Round 5
// 130.821 us; speedup vs baseline: 1.2383x; 1.0781x over previous
//
#include <hip/hip_runtime.h>
#include <hip/hip_bf16.h>

typedef __attribute__((ext_vector_type(4))) float f32x4;
typedef __attribute__((ext_vector_type(8))) short bf16x8;
typedef __attribute__((ext_vector_type(2))) unsigned int u32x2;
typedef unsigned short u16;
typedef unsigned int u32;

// ---------- helpers ----------

__device__ __forceinline__ u16 f2bf(float f) {
  union { float f; unsigned int u; } v;
  v.f = f;
  unsigned int r = (v.u + 0x7fffu + ((v.u >> 16) & 1u)) >> 16;
  return (u16)r;
}

// packed f32->bf16 convert (RNE), 2 floats -> 1 dword
__device__ __forceinline__ u32 pk2(float a, float b) {
  u32 r;
  asm("v_cvt_pk_bf16_f32 %0, %1, %2" : "=v"(r) : "v"(a), "v"(b));
  return r;
}

// async global->LDS, 16 bytes/lane; LDS dest = wave-uniform base + lane*16
__device__ __forceinline__ void async16(const void* g, const void* l) {
  __builtin_amdgcn_global_load_lds(
      (const __attribute__((address_space(1))) unsigned int*)(unsigned long)g,
      (__attribute__((address_space(3))) unsigned int*)(unsigned int)(unsigned long)l,
      16, 0, 0);
}

__device__ __forceinline__ void bar() {
  asm volatile("" ::: "memory");
  __builtin_amdgcn_s_barrier();
  asm volatile("" ::: "memory");
}

#define WAIT_LGKM0() asm volatile("s_waitcnt lgkmcnt(0)" ::: "memory")
#define WAIT_VM0()   asm volatile("s_waitcnt vmcnt(0)" ::: "memory")

// bank-balance swizzle: works for stride-1 row reads AND stride-4 row writes
#define G8(r) ((((r) >> 3) ^ (r)) & 7)

// ===================================================================
// GEMM A (fused transpose+convert): Pt[d][h] = sum_n V[n][d] * K[n][h]
// per batch: M=1024(d) N=1024(h) K=2048(n). BM=128, BN=256, BK=64.
// 512 thr = 8 waves (2M x 4N), per-wave 64x64. fp32 inputs reg-staged:
// 4x4 quad transpose in registers -> swizzled ds_write_b64.
// Single barrier per K-tile (drift schedule).
// ===================================================================
__global__ __launch_bounds__(512, 2) void gemmA(const float* __restrict__ V,
                                                const float* __restrict__ Kf,
                                                u16* __restrict__ Pt) {
  __shared__ u16 As[2][128][64];  // 32 KB (V^T tile, [d][n])
  __shared__ u16 Bs[2][256][64];  // 64 KB (K^T tile, [h][n])

  const int bid = blockIdx.x;
  const int b = bid & 7;          // batch -> XCD pin
  const int tile = bid >> 3;      // 0..31
  const int bn0 = (tile & 3) * 256;   // h
  const int bm0 = (tile >> 2) * 128;  // d

  const int tid = threadIdx.x;
  const int lane = tid & 63;
  const int wave = tid >> 6;
  const int wr = wave >> 2;  // 0..1 (M)
  const int wc = wave & 3;   // 0..3 (N)
  const int l16 = lane & 15;
  const int kh = lane >> 4;

  // stage maps: quads. A: dq = tid&31 (d), nq = tid>>5 (n). B: hq = tid&31.
  const int dq = tid & 31, nq = tid >> 5;  // nq 0..15

  const char* pV = (const char*)(V + (long)b * 2048 * 1024 +
                                 (long)(nq * 4) * 1024 + bm0 + dq * 4);
  const char* pK = (const char*)(Kf + (long)b * 2048 * 1024 +
                                 (long)(nq * 4) * 1024 + bn0 + dq * 4);

  // transposed write byte-offsets (within one buffer)
  int awo[4], bwo[2][4];
#pragma unroll
  for (int j = 0; j < 4; ++j) {
    int r = dq * 4 + j;
    awo[j] = r * 128 + (((nq >> 1) ^ G8(r)) * 16) + (nq & 1) * 8;
  }
#pragma unroll
  for (int h = 0; h < 2; ++h)
#pragma unroll
    for (int j = 0; j < 4; ++j) {
      int r = h * 128 + dq * 4 + j;
      bwo[h][j] = r * 128 + (((nq >> 1) ^ G8(r)) * 16) + (nq & 1) * 8;
    }

  // fragment read element-offsets
  int offA[2][2][2], offB[2][2][2];  // [q][f][ks]
#pragma unroll
  for (int q = 0; q < 2; ++q)
#pragma unroll
    for (int f = 0; f < 2; ++f) {
      int rA = q * 64 + wr * 32 + f * 16 + l16;
      int rB = q * 128 + wc * 32 + f * 16 + l16;
#pragma unroll
      for (int ks = 0; ks < 2; ++ks) {
        offA[q][f][ks] = rA * 64 + (((ks * 4 + kh) ^ G8(rA)) * 8);
        offB[q][f][ks] = rB * 64 + (((ks * 4 + kh) ^ G8(rB)) * 8);
      }
    }

  f32x4 acc[4][4] = {};
  f32x4 aq[4], bq[8];
  bf16x8 ar[2][2], br[4][2];

  // ---- prologue: load + convert tile 0 -> buf 0 ----
#pragma unroll
  for (int j = 0; j < 4; ++j) aq[j] = *(const f32x4*)(pV + j * 4096);
#pragma unroll
  for (int h = 0; h < 2; ++h)
#pragma unroll
    for (int j = 0; j < 4; ++j)
      bq[h * 4 + j] = *(const f32x4*)(pK + h * 512 + j * 4096);
  pV += 262144; pK += 262144;
  {
    char* dA = (char*)&As[0][0][0];
    char* dB = (char*)&Bs[0][0][0];
#pragma unroll
    for (int j = 0; j < 4; ++j) {
      u32x2 v; v.x = pk2(aq[0][j], aq[1][j]); v.y = pk2(aq[2][j], aq[3][j]);
      *(u32x2*)(dA + awo[j]) = v;
    }
#pragma unroll
    for (int h = 0; h < 2; ++h)
#pragma unroll
      for (int j = 0; j < 4; ++j) {
        u32x2 v; v.x = pk2(bq[h * 4 + 0][j], bq[h * 4 + 1][j]);
        v.y = pk2(bq[h * 4 + 2][j], bq[h * 4 + 3][j]);
        *(u32x2*)(dB + bwo[h][j]) = v;
      }
  }
  WAIT_LGKM0();
  bar();

  const int NT = 32;
  for (int t = 0; t < NT; ++t) {
    const int cur = t & 1, nxt = cur ^ 1;
    const bool g = (t + 1 < NT);
    const u16* Ab = &As[cur][0][0];
    const u16* Bb = &Bs[cur][0][0];

    // fragment reads: A half0 + all B
#pragma unroll
    for (int f = 0; f < 2; ++f)
#pragma unroll
      for (int ks = 0; ks < 2; ++ks)
        ar[f][ks] = *(const bf16x8*)(Ab + offA[0][f][ks]);
#pragma unroll
    for (int q = 0; q < 2; ++q)
#pragma unroll
      for (int f = 0; f < 2; ++f)
#pragma unroll
        for (int ks = 0; ks < 2; ++ks)
          br[q * 2 + f][ks] = *(const bf16x8*)(Bb + offB[q][f][ks]);

    // issue next-tile global loads early
    if (g) {
#pragma unroll
      for (int j = 0; j < 4; ++j) aq[j] = *(const f32x4*)(pV + j * 4096);
#pragma unroll
      for (int h = 0; h < 2; ++h)
#pragma unroll
        for (int j = 0; j < 4; ++j)
          bq[h * 4 + j] = *(const f32x4*)(pK + h * 512 + j * 4096);
      pV += 262144; pK += 262144;
    }

    // MMA half 0 (16 MFMA)
    __builtin_amdgcn_s_setprio(1);
#pragma unroll
    for (int f = 0; f < 2; ++f)
#pragma unroll
      for (int n = 0; n < 4; ++n)
#pragma unroll
        for (int ks = 0; ks < 2; ++ks)
          acc[f][n] = __builtin_amdgcn_mfma_f32_16x16x32_bf16(
              ar[f][ks], br[n][ks], acc[f][n], 0, 0, 0);
    __builtin_amdgcn_s_setprio(0);

    // fragment reads: A half1
#pragma unroll
    for (int f = 0; f < 2; ++f)
#pragma unroll
      for (int ks = 0; ks < 2; ++ks)
        ar[f][ks] = *(const bf16x8*)(Ab + offA[1][f][ks]);

    // convert + transposed LDS write of next tile
    if (g) {
      char* dA = (char*)&As[nxt][0][0];
      char* dB = (char*)&Bs[nxt][0][0];
#pragma unroll
      for (int j = 0; j < 4; ++j) {
        u32x2 v; v.x = pk2(aq[0][j], aq[1][j]); v.y = pk2(aq[2][j], aq[3][j]);
        *(u32x2*)(dA + awo[j]) = v;
      }
#pragma unroll
      for (int h = 0; h < 2; ++h)
#pragma unroll
        for (int j = 0; j < 4; ++j) {
          u32x2 v; v.x = pk2(bq[h * 4 + 0][j], bq[h * 4 + 1][j]);
          v.y = pk2(bq[h * 4 + 2][j], bq[h * 4 + 3][j]);
          *(u32x2*)(dB + bwo[h][j]) = v;
        }
    }

    // MMA half 1
    __builtin_amdgcn_s_setprio(1);
#pragma unroll
    for (int f = 0; f < 2; ++f)
#pragma unroll
      for (int n = 0; n < 4; ++n)
#pragma unroll
        for (int ks = 0; ks < 2; ++ks)
          acc[2 + f][n] = __builtin_amdgcn_mfma_f32_16x16x32_bf16(
              ar[f][ks], br[n][ks], acc[2 + f][n], 0, 0, 0);
    __builtin_amdgcn_s_setprio(0);

    WAIT_LGKM0();  // all my LDS writes visible before crossing
    bar();
  }

  // epilogue: C/D col = l16, row = kh*4 + r
  u16* Cb = Pt + (long)b * 1024 * 1024;
#pragma unroll
  for (int fm = 0; fm < 4; ++fm) {
    const int gm = bm0 + (fm >> 1) * 64 + wr * 32 + (fm & 1) * 16 + kh * 4;
#pragma unroll
    for (int fn = 0; fn < 4; ++fn) {
      const int gn = bn0 + (fn >> 1) * 128 + wc * 32 + (fn & 1) * 16 + l16;
#pragma unroll
      for (int r = 0; r < 4; ++r)
        Cb[(long)(gm + r) * 1024 + gn] = f2bf(acc[fm][fn][r]);
    }
  }
}

// ===================================================================
// GEMM B (fused convert): out[m][d] = sum_h Q[m][h] * Pt[d][h]
// per batch: M=2048 N=1024(d) K=1024(h). BM=256, BN=256, BK=64.
// Q fp32 reg-staged (no transpose); Pt bf16 via global_load_lds with
// pre-swizzled source. Single barrier per K-tile.
// ===================================================================
__global__ __launch_bounds__(512, 2) void gemmB(const float* __restrict__ Q,
                                                const u16* __restrict__ Pt,
                                                float* __restrict__ out) {
  __shared__ u16 As[2][256][64];      // Q tile, 64 KB
  __shared__ u16 Bs[2][2][128][64];   // Pt tile halves, 64 KB

  const int bid = blockIdx.x;
  const int b = bid & 7;
  const int tile = bid >> 3;              // 0..31
  const int bn0 = (tile & 3) * 256;       // d
  const int bm0 = (tile >> 2) * 256;      // m

  const int tid = threadIdx.x;
  const int lane = tid & 63;
  const int wave = tid >> 6;
  const int wr = wave >> 2;  // 0..1
  const int wc = wave & 3;   // 0..3
  const int l16 = lane & 15;
  const int kh = lane >> 4;

  // Q stage map: pass p -> row m = p*32 + (tid>>4), k quad = (tid&15)*4
  const int mrow = tid >> 4;          // 0..31
  const char* pQ = (const char*)(Q + (long)b * 2048 * 1024 +
                                 (long)(bm0 + mrow) * 1024 + (tid & 15) * 4);

  int qwo[8];
#pragma unroll
  for (int p = 0; p < 8; ++p) {
    int r = p * 32 + mrow;
    qwo[p] = r * 128 + ((((tid & 15) >> 1) ^ G8(r)) * 16) + (tid & 1) * 8;
  }

  // Pt gload staging: pre-swizzled global source, linear LDS dest
  int boff[2][2];
#pragma unroll
  for (int h = 0; h < 2; ++h)
#pragma unroll
    for (int i = 0; i < 2; ++i) {
      int u = tid + i * 512;
      int row = u >> 3, sl = (u & 7) ^ (row & 7);
      boff[h][i] = (bn0 + h * 128 + row) * 2048 + sl * 16;
    }
  const char* PtB = (const char*)(Pt + (long)b * 1024 * 1024);

  // fragment read offsets
  int offA[2][4][2];  // [qm][f][ks], G8 swizzle
#pragma unroll
  for (int q = 0; q < 2; ++q)
#pragma unroll
    for (int f = 0; f < 4; ++f) {
      int r = q * 128 + wr * 64 + f * 16 + l16;
#pragma unroll
      for (int ks = 0; ks < 2; ++ks)
        offA[q][f][ks] = r * 64 + (((ks * 4 + kh) ^ G8(r)) * 8);
    }
  int offBf[2][2];  // [g][ks] within half, old (row&7) swizzle
#pragma unroll
  for (int g_ = 0; g_ < 2; ++g_) {
    int r = wc * 32 + g_ * 16 + l16;
#pragma unroll
    for (int ks = 0; ks < 2; ++ks)
      offBf[g_][ks] = r * 64 + (((ks * 4 + kh) ^ (l16 & 7)) * 8);
  }

#define STG_PT(h, buf)                                                      \
  {                                                                         \
    _Pragma("unroll") for (int i_ = 0; i_ < 2; ++i_) {                      \
      async16(PtB + boff[h][i_],                                            \
              (char*)&Bs[buf][h][0][0] + (tid + i_ * 512) * 16);            \
      boff[h][i_] += 128;                                                   \
    }                                                                       \
  }

  f32x4 acc[8][4] = {};
  f32x4 qv[8];
  bf16x8 ar[4][2], br[4][2];

  // ---- prologue: tile 0 ----
#pragma unroll
  for (int p = 0; p < 8; ++p) qv[p] = *(const f32x4*)(pQ + p * 131072);
  STG_PT(0, 0);
  STG_PT(1, 0);
  {
    char* dA = (char*)&As[0][0][0];
#pragma unroll
    for (int p = 0; p < 8; ++p) {
      u32x2 v; v.x = pk2(qv[p].x, qv[p].y); v.y = pk2(qv[p].z, qv[p].w);
      *(u32x2*)(dA + qwo[p]) = v;
    }
  }
  pQ += 256;
  WAIT_VM0();
  WAIT_LGKM0();
  bar();

  const int NT = 16;
  for (int t = 0; t < NT; ++t) {
    const int cur = t & 1, nxt = cur ^ 1;
    const bool g = (t + 1 < NT);
    const u16* Ab = &As[cur][0][0];

    // fragment reads: A half0 + all B
#pragma unroll
    for (int f = 0; f < 4; ++f)
#pragma unroll
      for (int ks = 0; ks < 2; ++ks)
        ar[f][ks] = *(const bf16x8*)(Ab + offA[0][f][ks]);
#pragma unroll
    for (int qn = 0; qn < 2; ++qn)
#pragma unroll
      for (int g_ = 0; g_ < 2; ++g_)
#pragma unroll
        for (int ks = 0; ks < 2; ++ks)
          br[qn * 2 + g_][ks] =
              *(const bf16x8*)(&Bs[cur][qn][0][0] + offBf[g_][ks]);

    if (g) {
#pragma unroll
      for (int p = 0; p < 8; ++p) qv[p] = *(const f32x4*)(pQ + p * 131072);
      STG_PT(0, nxt);
      STG_PT(1, nxt);
    }

    // MMA half 0 (32 MFMA)
    __builtin_amdgcn_s_setprio(1);
#pragma unroll
    for (int f = 0; f < 4; ++f)
#pragma unroll
      for (int n = 0; n < 4; ++n)
#pragma unroll
        for (int ks = 0; ks < 2; ++ks)
          acc[f][n] = __builtin_amdgcn_mfma_f32_16x16x32_bf16(
              ar[f][ks], br[n][ks], acc[f][n], 0, 0, 0);
    __builtin_amdgcn_s_setprio(0);

    // fragment reads: A half1
#pragma unroll
    for (int f = 0; f < 4; ++f)
#pragma unroll
      for (int ks = 0; ks < 2; ++ks)
        ar[f][ks] = *(const bf16x8*)(Ab + offA[1][f][ks]);

    // convert + write next Q tile
    if (g) {
      char* dA = (char*)&As[nxt][0][0];
#pragma unroll
      for (int p = 0; p < 8; ++p) {
        u32x2 v; v.x = pk2(qv[p].x, qv[p].y); v.y = pk2(qv[p].z, qv[p].w);
        *(u32x2*)(dA + qwo[p]) = v;
      }
      pQ += 256;
    }

    // MMA half 1
    __builtin_amdgcn_s_setprio(1);
#pragma unroll
    for (int f = 0; f < 4; ++f)
#pragma unroll
      for (int n = 0; n < 4; ++n)
#pragma unroll
        for (int ks = 0; ks < 2; ++ks)
          acc[4 + f][n] = __builtin_amdgcn_mfma_f32_16x16x32_bf16(
              ar[f][ks], br[n][ks], acc[4 + f][n], 0, 0, 0);
    __builtin_amdgcn_s_setprio(0);

    if (g) WAIT_VM0();  // Pt gload_lds landed (cross-wave visibility)
    WAIT_LGKM0();       // my ds_writes visible
    bar();
  }

  // epilogue
  float* Cf = out + (long)b * 2048 * 1024;
#pragma unroll
  for (int fm = 0; fm < 8; ++fm) {
    const int gm = bm0 + (fm >> 2) * 128 + wr * 64 + (fm & 3) * 16 + kh * 4;
#pragma unroll
    for (int fn = 0; fn < 4; ++fn) {
      const int gn = bn0 + (fn >> 1) * 128 + wc * 32 + (fn & 1) * 16 + l16;
#pragma unroll
      for (int r = 0; r < 4; ++r)
        Cf[(long)(gm + r) * 1024 + gn] = acc[fm][fn][r];
    }
  }
#undef STG_PT
}

// ---------- launch ----------

extern "C" void kernel_launch(void* const* d_in, const int* in_sizes, int n_in,
                              void* d_out, int out_size, void* d_ws, size_t ws_size,
                              hipStream_t stream) {
  const float* Q  = (const float*)d_in[0];
  const float* Kf = (const float*)d_in[1];
  // d_in[2] = span   (unused by the reference's returned value)
  const float* V  = (const float*)d_in[3];
  // d_in[4] = key_pe (unused)
  float* out = (float*)d_out;

  // workspace: Pt [8][1024][1024] bf16 = 16 MB
  u16* Pt = (u16*)d_ws;

  // GEMM A: Pt[d][h] = sum_n V[n][d]*K[n][h]; 8 batches x 32 tiles = 256 blocks
  gemmA<<<256, 512, 0, stream>>>(V, Kf, Pt);

  // GEMM B: out[m][d] = sum_h Q[m][h]*Pt[d][h]; 256 blocks
  gemmB<<<256, 512, 0, stream>>>(Q, Pt, out);
}